// Round 1
// baseline (1526.981 us; speedup 1.0000x reference)
//
#include <hip/hip_runtime.h>
#include <cstdint>
#include <cstddef>

#define NB 16
#define NC 84
#define NA 33600
#define NCLS 80
#define TOPK 1024
#define SCORE_THR 0.005f
#define IOU_THR 0.5f

// ---- 64-bit sort key: (monotonic fp32) << 32 | ~index ----------------------
// Larger key == (higher score, then lower index) -> matches jax.lax.top_k
// tie-breaking (stable, lower index first). Keys are unique (index embedded).
__device__ __forceinline__ uint64_t make_key(float f, int a) {
    unsigned u = __float_as_uint(f);
    u = (u & 0x80000000u) ? ~u : (u | 0x80000000u);
    return ((uint64_t)u << 32) | (uint32_t)(~(uint32_t)a);
}
__device__ __forceinline__ float key_val(uint64_t k) {
    unsigned u = (unsigned)(k >> 32);
    u = (u & 0x80000000u) ? (u & 0x7FFFFFFFu) : ~u;
    return __uint_as_float(u);
}
__device__ __forceinline__ int key_idx(uint64_t k) {
    return (int)(~(uint32_t)(k & 0xFFFFFFFFu));
}

// ---- Phase 1: per-anchor max/argmax over 80 classes ------------------------
__global__ __launch_bounds__(256) void score_kernel(const float* __restrict__ x,
                                                    float* __restrict__ sval,
                                                    int* __restrict__ cid) {
    int gid = blockIdx.x * 256 + threadIdx.x;
    if (gid >= NB * NA) return;
    int b = gid / NA;
    int a = gid - b * NA;
    const float* p = x + (size_t)b * NC * NA + (size_t)4 * NA + a;
    float best = p[0];
    int bc = 0;
#pragma unroll 4
    for (int c = 1; c < NCLS; ++c) {
        float v = p[(size_t)c * NA];
        if (v > best) { best = v; bc = c; }   // strict > keeps first occurrence (argmax semantics)
    }
    sval[gid] = (best > SCORE_THR) ? best : -INFINITY;
    cid[gid] = bc;
}

// ---- Phase 2: exact top-1024 per batch (radix select + bitonic sort) -------
__global__ __launch_bounds__(256) void topk_kernel(const float* __restrict__ sval,
                                                   float* __restrict__ topval,
                                                   int* __restrict__ topidx) {
    const int b = blockIdx.x;
    const int tid = threadIdx.x;
    __shared__ unsigned hist[256];
    __shared__ uint64_t sh_prefix;
    __shared__ unsigned sh_r, sh_cnt;
    __shared__ uint64_t lkeys[TOPK];
    const float* sv = sval + (size_t)b * NA;

    if (tid == 0) { sh_prefix = 0ULL; sh_r = TOPK; sh_cnt = 0; }
    __syncthreads();

    // MSB-first 8-bit radix select for the exact 1024th-largest 64-bit key.
    for (int shift = 56; shift >= 0; shift -= 8) {
        hist[tid] = 0;
        __syncthreads();
        uint64_t pref = sh_prefix;
        uint64_t hm = (shift == 56) ? 0ULL : ((~0ULL) << (shift + 8));
        for (int a = tid; a < NA; a += 256) {
            uint64_t key = make_key(sv[a], a);
            if ((key & hm) == (pref & hm))
                atomicAdd(&hist[(unsigned)(key >> shift) & 255u], 1u);
        }
        __syncthreads();
        if (tid == 0) {
            unsigned cum = 0, r = sh_r;
            for (int d = 255; d >= 0; --d) {
                unsigned h = hist[d];
                cum += h;
                if (cum >= r) {
                    sh_prefix = pref | ((uint64_t)(unsigned)d << shift);
                    sh_r = r - (cum - h);
                    break;
                }
            }
        }
        __syncthreads();
    }
    const uint64_t kth = sh_prefix;  // exact 1024th-largest key (keys unique)

    // Gather: exactly 1024 keys are >= kth.
    for (int a = tid; a < NA; a += 256) {
        uint64_t key = make_key(sv[a], a);
        if (key >= kth) {
            unsigned p = atomicAdd(&sh_cnt, 1u);
            if (p < TOPK) lkeys[p] = key;
        }
    }
    __syncthreads();

    // Bitonic sort, descending.
    for (int k = 2; k <= TOPK; k <<= 1) {
        for (int j = k >> 1; j > 0; j >>= 1) {
            for (int i = tid; i < TOPK; i += 256) {
                int ixj = i ^ j;
                if (ixj > i) {
                    uint64_t A = lkeys[i], B = lkeys[ixj];
                    bool up = ((i & k) == 0);
                    if (up ? (A < B) : (A > B)) { lkeys[i] = B; lkeys[ixj] = A; }
                }
            }
            __syncthreads();
        }
    }

    for (int i = tid; i < TOPK; i += 256) {
        uint64_t key = lkeys[i];
        topval[b * TOPK + i] = key_val(key);
        topidx[b * TOPK + i] = key_idx(key);
    }
}

// ---- Phase 3: gather boxes + sequential greedy NMS (1 wave / batch) --------
// Lane l holds boxes k = s*64 + l for s in [0,16). keep state = 16-bit mask in
// a register; keep[i] broadcast via __shfl (single wave -> lockstep, no
// barrier needed; keep[i] is final by step i since only steps < i modify it).
__global__ __launch_bounds__(64) void nms_kernel(const float* __restrict__ x,
                                                 const int* __restrict__ cid,
                                                 const float* __restrict__ topval,
                                                 const int* __restrict__ topidx,
                                                 float* __restrict__ out) {
    const int b = blockIdx.x;
    const int l = threadIdx.x;  // 0..63
    __shared__ float sb[TOPK][5];  // x1,y1,x2,y2,area  (broadcast reads)

    float bx1[16], by1[16], bx2[16], by2[16], bar[16], bsc[16];
    int bcl[16];
    unsigned keep = 0;

#pragma unroll
    for (int s = 0; s < 16; ++s) {
        int k = s * 64 + l;
        int idx = topidx[b * TOPK + k];
        float sc = topval[b * TOPK + k];
        const float* p = x + (size_t)b * NC * NA + idx;
        float x1 = p[0], y1 = p[NA], x2 = p[2 * NA], y2 = p[3 * NA];
        float ar = (x2 - x1) * (y2 - y1);
        bx1[s] = x1; by1[s] = y1; bx2[s] = x2; by2[s] = y2;
        bar[s] = ar; bsc[s] = sc;
        bcl[s] = cid[b * NA + idx];
        sb[k][0] = x1; sb[k][1] = y1; sb[k][2] = x2; sb[k][3] = y2; sb[k][4] = ar;
        if (sc > SCORE_THR) keep |= (1u << s);  // valid = top_s > thr
    }
    __syncthreads();

    for (int i = 0; i < TOPK; ++i) {
        int li = i & 63, si = i >> 6;
        unsigned km = __shfl(keep, li, 64);
        if (!((km >> si) & 1u)) continue;  // wave-uniform skip
        float ix1 = sb[i][0], iy1 = sb[i][1], ix2 = sb[i][2], iy2 = sb[i][3], ia = sb[i][4];
#pragma unroll
        for (int s = 0; s < 16; ++s) {
            int k = s * 64 + l;
            if (k > i && ((keep >> s) & 1u)) {
                float ltx = fmaxf(ix1, bx1[s]);
                float lty = fmaxf(iy1, by1[s]);
                float rbx = fminf(ix2, bx2[s]);
                float rby = fminf(iy2, by2[s]);
                float w = fmaxf(rbx - ltx, 0.0f);
                float h = fmaxf(rby - lty, 0.0f);
                float inter = w * h;
                float uni = ia + bar[s] - inter;
                float iou = inter / fmaxf(uni, 1e-9f);
                if (iou > IOU_THR) keep &= ~(1u << s);
            }
        }
    }

    // Epilogue: out[b,k,0:6] = keep ? [box, score, cid] : 0 ; keep flags as f32.
#pragma unroll
    for (int s = 0; s < 16; ++s) {
        int k = s * 64 + l;
        bool kp = (keep >> s) & 1u;
        float* po = out + ((size_t)(b * TOPK + k)) * 6;
        po[0] = kp ? bx1[s] : 0.0f;
        po[1] = kp ? by1[s] : 0.0f;
        po[2] = kp ? bx2[s] : 0.0f;
        po[3] = kp ? by2[s] : 0.0f;
        po[4] = kp ? bsc[s] : 0.0f;
        po[5] = kp ? (float)bcl[s] : 0.0f;
        out[(size_t)NB * TOPK * 6 + b * TOPK + k] = kp ? 1.0f : 0.0f;
    }
}

extern "C" void kernel_launch(void* const* d_in, const int* in_sizes, int n_in,
                              void* d_out, int out_size, void* d_ws, size_t ws_size,
                              hipStream_t stream) {
    const float* x = (const float*)d_in[0];
    float* out = (float*)d_out;
    char* ws = (char*)d_ws;

    float* sval  = (float*)ws;                                    // NB*NA floats
    int*   cid   = (int*)(ws + (size_t)NB * NA * 4);              // NB*NA ints
    float* tval  = (float*)(ws + (size_t)NB * NA * 8);            // NB*TOPK floats
    int*   tidx  = (int*)(ws + (size_t)NB * NA * 8 + (size_t)NB * TOPK * 4);

    int total = NB * NA;
    score_kernel<<<(total + 255) / 256, 256, 0, stream>>>(x, sval, cid);
    topk_kernel<<<NB, 256, 0, stream>>>(sval, tval, tidx);
    nms_kernel<<<NB, 64, 0, stream>>>(x, cid, tval, tidx, out);
}

// Round 2
// 614.484 us; speedup vs baseline: 2.4850x; 2.4850x over previous
//
#include <hip/hip_runtime.h>
#include <cstdint>
#include <cstddef>

#define NB 16
#define NC 84
#define NA 33600
#define NCLS 80
#define TOPK 1024
#define SCORE_THR 0.005f
#define IOU_THR 0.5f

// ---- 64-bit sort key: (monotonic fp32) << 32 | ~index ----------------------
__device__ __forceinline__ uint64_t make_key(float f, int a) {
    unsigned u = __float_as_uint(f);
    u = (u & 0x80000000u) ? ~u : (u | 0x80000000u);
    return ((uint64_t)u << 32) | (uint32_t)(~(uint32_t)a);
}
__device__ __forceinline__ float key_val(uint64_t k) {
    unsigned u = (unsigned)(k >> 32);
    u = (u & 0x80000000u) ? (u & 0x7FFFFFFFu) : ~u;
    return __uint_as_float(u);
}
__device__ __forceinline__ int key_idx(uint64_t k) {
    return (int)(~(uint32_t)(k & 0xFFFFFFFFu));
}

// ---- Phase 1: per-anchor max/argmax over 80 classes ------------------------
__global__ __launch_bounds__(256) void score_kernel(const float* __restrict__ x,
                                                    float* __restrict__ sval,
                                                    int* __restrict__ cid) {
    int gid = blockIdx.x * 256 + threadIdx.x;
    if (gid >= NB * NA) return;
    int b = gid / NA;
    int a = gid - b * NA;
    const float* p = x + (size_t)b * NC * NA + (size_t)4 * NA + a;
    float best = p[0];
    int bc = 0;
#pragma unroll 4
    for (int c = 1; c < NCLS; ++c) {
        float v = p[(size_t)c * NA];
        if (v > best) { best = v; bc = c; }   // strict > == first-occurrence argmax
    }
    sval[gid] = (best > SCORE_THR) ? best : -INFINITY;
    cid[gid] = bc;
}

// ---- Phase 2: exact top-1024 per batch (radix select + bitonic sort) -------
__global__ __launch_bounds__(256) void topk_kernel(const float* __restrict__ sval,
                                                   float* __restrict__ topval,
                                                   int* __restrict__ topidx) {
    const int b = blockIdx.x;
    const int tid = threadIdx.x;
    __shared__ unsigned hist[256];
    __shared__ uint64_t sh_prefix;
    __shared__ unsigned sh_r, sh_cnt;
    __shared__ uint64_t lkeys[TOPK];
    const float* sv = sval + (size_t)b * NA;

    if (tid == 0) { sh_prefix = 0ULL; sh_r = TOPK; sh_cnt = 0; }
    __syncthreads();

    for (int shift = 56; shift >= 0; shift -= 8) {
        hist[tid] = 0;
        __syncthreads();
        uint64_t pref = sh_prefix;
        uint64_t hm = (shift == 56) ? 0ULL : ((~0ULL) << (shift + 8));
        for (int a = tid; a < NA; a += 256) {
            uint64_t key = make_key(sv[a], a);
            if ((key & hm) == (pref & hm))
                atomicAdd(&hist[(unsigned)(key >> shift) & 255u], 1u);
        }
        __syncthreads();
        if (tid == 0) {
            unsigned cum = 0, r = sh_r;
            for (int d = 255; d >= 0; --d) {
                unsigned h = hist[d];
                cum += h;
                if (cum >= r) {
                    sh_prefix = pref | ((uint64_t)(unsigned)d << shift);
                    sh_r = r - (cum - h);
                    break;
                }
            }
        }
        __syncthreads();
    }
    const uint64_t kth = sh_prefix;

    for (int a = tid; a < NA; a += 256) {
        uint64_t key = make_key(sv[a], a);
        if (key >= kth) {
            unsigned p = atomicAdd(&sh_cnt, 1u);
            if (p < TOPK) lkeys[p] = key;
        }
    }
    __syncthreads();

    for (int k = 2; k <= TOPK; k <<= 1) {
        for (int j = k >> 1; j > 0; j >>= 1) {
            for (int i = tid; i < TOPK; i += 256) {
                int ixj = i ^ j;
                if (ixj > i) {
                    uint64_t A = lkeys[i], B = lkeys[ixj];
                    bool up = ((i & k) == 0);
                    if (up ? (A < B) : (A > B)) { lkeys[i] = B; lkeys[ixj] = A; }
                }
            }
            __syncthreads();
        }
    }

    for (int i = tid; i < TOPK; i += 256) {
        uint64_t key = lkeys[i];
        topval[b * TOPK + i] = key_val(key);
        topidx[b * TOPK + i] = key_idx(key);
    }
}

// ---- Phase 3a: gather top-1024 boxes SoA + class ids -----------------------
__global__ __launch_bounds__(256) void boxes_kernel(const float* __restrict__ x,
                                                    const int* __restrict__ cid,
                                                    const int* __restrict__ tidx,
                                                    float* __restrict__ bx1, float* __restrict__ by1,
                                                    float* __restrict__ bx2, float* __restrict__ by2,
                                                    float* __restrict__ bar, int* __restrict__ tcid) {
    int b = blockIdx.x;
    int base = b << 10;
    const float* xb = x + (size_t)b * NC * NA;
    for (int k = threadIdx.x; k < TOPK; k += 256) {
        int idx = tidx[base + k];
        float x1 = xb[idx], y1 = xb[NA + idx], x2 = xb[2 * NA + idx], y2 = xb[3 * NA + idx];
        bx1[base + k] = x1; by1[base + k] = y1;
        bx2[base + k] = x2; by2[base + k] = y2;
        bar[base + k] = (x2 - x1) * (y2 - y1);
        tcid[base + k] = cid[b * NA + idx];
    }
}

// ---- Phase 3b: parallel suppression bit-matrix -----------------------------
// Block = 16 rows x 16 words; thread (r,w) computes M[i=r][j in w*64..w*64+63].
// Boxes staged in LDS with +1 pad per 64 so stride-64 j accesses are
// conflict-free (bank = (65w + jj) % 32 distinct across the 16 w's).
#define LDSPAD(j) ((j) + ((j) >> 6))
__global__ __launch_bounds__(256) void maskbuild_kernel(const float* __restrict__ bx1,
                                                        const float* __restrict__ by1,
                                                        const float* __restrict__ bx2,
                                                        const float* __restrict__ by2,
                                                        const float* __restrict__ bar,
                                                        const float* __restrict__ tval,
                                                        uint64_t* __restrict__ M,
                                                        int* __restrict__ rowflag) {
    int b = blockIdx.x >> 6;
    int r0 = (blockIdx.x & 63) << 4;
    int t = threadIdx.x;
    int r = r0 + (t >> 4);
    int w = t & 15;
    int base = b << 10;
    __shared__ float sx1[TOPK + 16], sy1[TOPK + 16], sx2[TOPK + 16], sy2[TOPK + 16], sar[TOPK + 16];
    __shared__ int anyf[256];

    for (int j = t; j < TOPK; j += 256) {
        int ji = LDSPAD(j);
        sx1[ji] = bx1[base + j]; sy1[ji] = by1[base + j];
        sx2[ji] = bx2[base + j]; sy2[ji] = by2[base + j];
        sar[ji] = bar[base + j];
    }
    __syncthreads();

    int ri = LDSPAD(r);
    float ix1 = sx1[ri], iy1 = sy1[ri], ix2 = sx2[ri], iy2 = sy2[ri], ia = sar[ri];
    uint64_t m = 0;
#pragma unroll 8
    for (int jj = 0; jj < 64; ++jj) {
        int j = (w << 6) + jj;
        int ji = w * 65 + jj;
        float ltx = fmaxf(ix1, sx1[ji]);
        float lty = fmaxf(iy1, sy1[ji]);
        float rbx = fminf(ix2, sx2[ji]);
        float rby = fminf(iy2, sy2[ji]);
        float ww = fmaxf(rbx - ltx, 0.0f);
        float hh = fmaxf(rby - lty, 0.0f);
        float inter = ww * hh;
        float uni = ia + sar[ji] - inter;      // same op order as reference
        float iou = inter / fmaxf(uni, 1e-9f);
        if (j > r && iou > IOU_THR) m |= (1ULL << jj);
    }
    M[((size_t)(base + r) << 4) + w] = m;
    anyf[t] = (m != 0ULL);
    __syncthreads();
    if (w == 0) {
        int any = 0;
#pragma unroll
        for (int q = 0; q < 16; ++q) any |= anyf[t + q];
        bool valid = tval[base + r] > SCORE_THR;   // invalid rows never suppress
        rowflag[base + r] = (any && valid) ? 1 : 0;
    }
}

// ---- Phase 3c: serial greedy sweep over nonzero rows only + epilogue -------
// One wave per batch. Lane w<16 owns remv word w. Zero-mask rows are no-ops
// on the suppression state, so only rows with (nonzero mask && valid) need
// the serial pass. Final keep[j] = valid[j] & ~remv[j].
__global__ __launch_bounds__(64) void sweep_kernel(const uint64_t* __restrict__ M,
                                                   const int* __restrict__ rowflag,
                                                   const float* __restrict__ tval,
                                                   const int* __restrict__ tcid,
                                                   const float* __restrict__ bx1,
                                                   const float* __restrict__ by1,
                                                   const float* __restrict__ bx2,
                                                   const float* __restrict__ by2,
                                                   float* __restrict__ out) {
    int b = blockIdx.x;
    int l = threadIdx.x;
    int base = b << 10;
    __shared__ int list[TOPK];

    float tv[16];
#pragma unroll
    for (int s = 0; s < 16; ++s) tv[s] = tval[base + (s << 6) + l];

    // valid bitmask word for group s lives in lane s
    uint64_t vword = 0;
#pragma unroll
    for (int s = 0; s < 16; ++s) {
        uint64_t bal = __ballot(tv[s] > SCORE_THR);
        if (l == s) vword = bal;
    }

    // ordered compaction of nonzero+valid rows
    int cnt = 0;
#pragma unroll
    for (int s = 0; s < 16; ++s) {
        int flag = rowflag[base + (s << 6) + l];
        uint64_t m = __ballot(flag != 0);
        if (flag) {
            int pos = cnt + __popcll(m & ((1ULL << l) - 1ULL));
            list[pos] = (s << 6) + l;
        }
        cnt += __popcll(m);
    }
    __syncthreads();

    uint64_t remv = 0;
    int w = l & 15;
    for (int it = 0; it < cnt; ++it) {
        int i = list[it];
        uint64_t row = M[((size_t)(base + i) << 4) + w];
        uint64_t rb = __shfl(remv, i >> 6, 64);
        bool kept = !((rb >> (i & 63)) & 1ULL);
        remv |= kept ? row : 0ULL;
    }

    uint64_t kf = vword & ~remv;   // valid in lane s for group s
#pragma unroll
    for (int s = 0; s < 16; ++s) {
        uint64_t kw = __shfl(kf, s, 64);
        bool kp = (kw >> l) & 1ULL;
        int k = (s << 6) + l;
        float x1 = bx1[base + k], y1 = by1[base + k];
        float x2 = bx2[base + k], y2 = by2[base + k];
        float* po = out + ((size_t)(base + k)) * 6;
        po[0] = kp ? x1 : 0.0f;
        po[1] = kp ? y1 : 0.0f;
        po[2] = kp ? x2 : 0.0f;
        po[3] = kp ? y2 : 0.0f;
        po[4] = kp ? tv[s] : 0.0f;
        po[5] = kp ? (float)tcid[base + k] : 0.0f;
        out[(size_t)NB * TOPK * 6 + base + k] = kp ? 1.0f : 0.0f;
    }
}

extern "C" void kernel_launch(void* const* d_in, const int* in_sizes, int n_in,
                              void* d_out, int out_size, void* d_ws, size_t ws_size,
                              hipStream_t stream) {
    const float* x = (const float*)d_in[0];
    float* out = (float*)d_out;
    char* ws = (char*)d_ws;

    size_t off = 0;
    auto alloc = [&](size_t bytes) { void* p = ws + off; off = (off + bytes + 255) & ~(size_t)255; return p; };
    float*    sval    = (float*)alloc((size_t)NB * NA * 4);
    int*      cid     = (int*)alloc((size_t)NB * NA * 4);
    float*    tval    = (float*)alloc((size_t)NB * TOPK * 4);
    int*      tidx    = (int*)alloc((size_t)NB * TOPK * 4);
    float*    bx1     = (float*)alloc((size_t)NB * TOPK * 4);
    float*    by1     = (float*)alloc((size_t)NB * TOPK * 4);
    float*    bx2     = (float*)alloc((size_t)NB * TOPK * 4);
    float*    by2     = (float*)alloc((size_t)NB * TOPK * 4);
    float*    bar     = (float*)alloc((size_t)NB * TOPK * 4);
    int*      tcid    = (int*)alloc((size_t)NB * TOPK * 4);
    uint64_t* M       = (uint64_t*)alloc((size_t)NB * TOPK * 16 * 8);
    int*      rowflag = (int*)alloc((size_t)NB * TOPK * 4);

    int total = NB * NA;
    score_kernel<<<(total + 255) / 256, 256, 0, stream>>>(x, sval, cid);
    topk_kernel<<<NB, 256, 0, stream>>>(sval, tval, tidx);
    boxes_kernel<<<NB, 256, 0, stream>>>(x, cid, tidx, bx1, by1, bx2, by2, bar, tcid);
    maskbuild_kernel<<<NB * 64, 256, 0, stream>>>(bx1, by1, bx2, by2, bar, tval, M, rowflag);
    sweep_kernel<<<NB, 64, 0, stream>>>(M, rowflag, tval, tcid, bx1, by1, bx2, by2, out);
}